// Round 15
// baseline (120.295 us; speedup 1.0000x reference)
//
#include <hip/hip_runtime.h>

// SigLIP contrastive loss:
//   logits = emb1 @ emb2^T / 0.07           [B,B], B=8192, D=1024
//   loss = ( sum_i softplus(-l_ii) + sum_{i!=j} softplus(l_ij) ) / B
// R15: register-level fragment double-buffer. R8-R14 invariant: MFMAs wait
// on same-iteration ds_reads (serial ~1985 cyc/K-tile, MfmaUtil 28%). Now:
// iter T issues ds_reads of tile T+1 into the alternate register set while
// MFMAs consume tile T's set -> MFMA phase never waits on LDS. Needs tile
// T+1 LDS-resident at iter T start -> depth-2 staging, triple-buffered LDS
// (3x48KB). 256x128 tile, 8 waves, 1 block/CU, 2 waves/SIMD. Hand-unrolled
// iterations with literal register-set names (no dynamic indexing).

#define B_DIM 8192
#define K_DIM 1024
#define BKB 128                // K bytes per K-tile
#define NT (K_DIM / BKB)       // 8 K-tiles
#define BRICK 16384            // one (128-row panel, K-tile) brick
#define PANEL_BYTES (NT * BRICK)
#define BUFSZ 49152            // LDS buffer: A 32K + B 16K

typedef int i32x4 __attribute__((ext_vector_type(4)));
typedef int i32x8 __attribute__((ext_vector_type(8)));
typedef float f32x4 __attribute__((ext_vector_type(4)));

// f32 -> fp8 e4m3 brick permutation (PANEL=128). One thread = 16 out bytes.
__device__ __forceinline__ void brick_store(const float* __restrict__ in,
                                            unsigned char* __restrict__ out,
                                            float scale, int i) {
  const int o = i * 16;
  const int b = o >> 14;                  // brick index
  const int p = b >> 3, t = b & 7;        // panel, K-tile
  const int w = o & (BRICK - 1);
  const int fb = w >> 11;
  const int h = (w >> 10) & 1;
  const int kch = (w >> 8) & 3;
  const int lr = (w >> 4) & 15;
  const int row = p * 128 + fb * 16 + lr;
  const int kb = t * 128 + kch * 32 + h * 16;
  const float4* src = (const float4*)(in + (size_t)row * K_DIM + kb);
  float4 v0 = src[0], v1 = src[1], v2 = src[2], v3 = src[3];
  unsigned w0 = 0, w1 = 0, w2 = 0, w3 = 0;
  w0 = __builtin_amdgcn_cvt_pk_fp8_f32(v0.x * scale, v0.y * scale, w0, 0);
  w0 = __builtin_amdgcn_cvt_pk_fp8_f32(v0.z * scale, v0.w * scale, w0, 1);
  w1 = __builtin_amdgcn_cvt_pk_fp8_f32(v1.x * scale, v1.y * scale, w1, 0);
  w1 = __builtin_amdgcn_cvt_pk_fp8_f32(v1.z * scale, v1.w * scale, w1, 1);
  w2 = __builtin_amdgcn_cvt_pk_fp8_f32(v2.x * scale, v2.y * scale, w2, 0);
  w2 = __builtin_amdgcn_cvt_pk_fp8_f32(v2.z * scale, v2.w * scale, w2, 1);
  w3 = __builtin_amdgcn_cvt_pk_fp8_f32(v3.x * scale, v3.y * scale, w3, 0);
  w3 = __builtin_amdgcn_cvt_pk_fp8_f32(v3.z * scale, v3.w * scale, w3, 1);
  *(uint4*)(out + o) = make_uint4(w0, w1, w2, w3);
}

__global__ __launch_bounds__(256) void cvt_fused(
    const float* __restrict__ e1, const float* __restrict__ e2,
    unsigned char* __restrict__ A8, unsigned char* __restrict__ B8,
    int nbA, float scaleA) {
  const int blk = blockIdx.x;
  if (blk < nbA)
    brick_store(e1, A8, scaleA, blk * 256 + threadIdx.x);
  else
    brick_store(e2, B8, 1.0f, (blk - nbA) * 256 + threadIdx.x);
}

// Cheap softplus accumulate: softplus(x) = max(x,0) + log(1+exp(-|x|)).
template <bool DIAG>
__device__ __forceinline__ float softplus_sum(const f32x4 (&acc)[4][4],
                                              int rbase, int cbase) {
  float lin = 0.f, cor = 0.f;
#pragma unroll
  for (int m = 0; m < 4; ++m) {
#pragma unroll
    for (int n = 0; n < 4; ++n) {
#pragma unroll
      for (int r = 0; r < 4; ++r) {
        float x = acc[m][n][r];
        if (DIAG) {
          int row = rbase + m * 16 + r;
          int col = cbase + n * 16;
          if (row == col) x = -x;  // diagonal: softplus(-l_ii)
        }
        lin += fmaxf(x, 0.f);
        cor += __logf(1.f + __expf(-fabsf(x)));
      }
    }
  }
  return lin + cor;
}

// Staging: 48 KB/K-tile = 48 linear 1024B slices; wave w takes A slices
// (w&3)*4+q of panel (w>>2), and B slices w*2+q. 6 issues per wave.
#define STAGEA(SB, Q, TI)                                                     \
  __builtin_amdgcn_global_load_lds(                                           \
      (const __attribute__((address_space(1))) void*)(const void*)(           \
          srcA + (TI) * BRICK + (Q) * 1024),                                  \
      (__attribute__((address_space(3))) void*)(void*)(                       \
          lds + (SB) + dA + (Q) * 1024),                                      \
      16, 0, 0)
#define STAGEB(SB, Q, TI)                                                     \
  __builtin_amdgcn_global_load_lds(                                           \
      (const __attribute__((address_space(1))) void*)(const void*)(           \
          srcB + (TI) * BRICK + (Q) * 1024),                                  \
      (__attribute__((address_space(3))) void*)(void*)(                       \
          lds + (SB) + dB + (Q) * 1024),                                      \
      16, 0, 0)
#define STAGE6(SB, TI)                                                        \
  STAGEA(SB, 0, TI); STAGEA(SB, 1, TI); STAGEA(SB, 2, TI); STAGEA(SB, 3, TI); \
  STAGEB(SB, 0, TI); STAGEB(SB, 1, TI)

// Fragment read: two conflict-free ds_read_b128 (lane*16 stride) + combine.
#define LDA(OUT, RB, M)                                                       \
  {                                                                           \
    const unsigned char* _b =                                                 \
        ldsL + ((RB) + ((wr >> 1) * 16384) + (((wr & 1) * 4 + (M)) << 11));   \
    i32x4 _lo = *(const i32x4*)(_b);                                          \
    i32x4 _hi = *(const i32x4*)(_b + 1024);                                   \
    OUT = __builtin_shufflevector(_lo, _hi, 0, 1, 2, 3, 4, 5, 6, 7);          \
  }
#define LDB(OUT, RB, N)                                                       \
  {                                                                           \
    const unsigned char* _b = ldsL + ((RB) + 32768 + ((wc * 4 + (N)) << 11)); \
    i32x4 _lo = *(const i32x4*)(_b);                                          \
    i32x4 _hi = *(const i32x4*)(_b + 1024);                                   \
    OUT = __builtin_shufflevector(_lo, _hi, 0, 1, 2, 3, 4, 5, 6, 7);          \
  }
#define READS(RB, FA, FB)                                                     \
  LDA(FA[0], RB, 0); LDB(FB[0], RB, 0); LDB(FB[1], RB, 1);                    \
  LDB(FB[2], RB, 2); LDB(FB[3], RB, 3);                                       \
  LDA(FA[1], RB, 1); LDA(FA[2], RB, 2); LDA(FA[3], RB, 3)

#define MFMA1(AF, BF, M, N)                                                   \
  acc[M][N] = __builtin_amdgcn_mfma_scale_f32_16x16x128_f8f6f4(               \
      AF, BF, acc[M][N], 0, 0, 0, 127, 0, 127)
#define MFMAS(FA, FB)                                                         \
  __builtin_amdgcn_s_setprio(1);                                              \
  MFMA1(FA[0], FB[0], 0, 0); MFMA1(FA[0], FB[1], 0, 1);                       \
  MFMA1(FA[0], FB[2], 0, 2); MFMA1(FA[0], FB[3], 0, 3);                       \
  MFMA1(FA[1], FB[0], 1, 0); MFMA1(FA[1], FB[1], 1, 1);                       \
  MFMA1(FA[1], FB[2], 1, 2); MFMA1(FA[1], FB[3], 1, 3);                       \
  MFMA1(FA[2], FB[0], 2, 0); MFMA1(FA[2], FB[1], 2, 1);                       \
  MFMA1(FA[2], FB[2], 2, 2); MFMA1(FA[2], FB[3], 2, 3);                       \
  MFMA1(FA[3], FB[0], 3, 0); MFMA1(FA[3], FB[1], 3, 1);                       \
  MFMA1(FA[3], FB[2], 3, 2); MFMA1(FA[3], FB[3], 3, 3);                       \
  __builtin_amdgcn_s_setprio(0)

// One pipelined iteration (T literal). Compute tile T from FAc/FBc while
// prefetching tile T+1's fragments into FAn/FBn and staging tile T+2.
#define ITER(T, FAc, FBc, FAn, FBn)                                           \
  {                                                                           \
    if ((T) < NT - 2) { STAGE6((((T) + 2) % 3) * BUFSZ, (T) + 2); }           \
    if ((T) < NT - 2) {                                                       \
      asm volatile("s_waitcnt vmcnt(6)" ::: "memory");                        \
    } else if ((T) == NT - 2) {                                               \
      asm volatile("s_waitcnt vmcnt(0)" ::: "memory");                        \
    }                                                                         \
    if ((T) < NT - 1) {                                                       \
      __builtin_amdgcn_s_barrier();                                           \
      __builtin_amdgcn_sched_barrier(0);                                      \
      READS((((T) + 1) % 3) * BUFSZ, FAn, FBn);                               \
    }                                                                         \
    MFMAS(FAc, FBc);                                                          \
  }

__global__ __launch_bounds__(512, 1) void siglip_gemm(
    const unsigned char* __restrict__ A8,
    const unsigned char* __restrict__ B8,
    float* __restrict__ partials) {
  __shared__ unsigned char lds[3 * BUFSZ];  // 144 KB triple buffer
  __shared__ float wsum[8];

  const int tid = threadIdx.x;
  const int wave = tid >> 6;
  const int lane = tid & 63;
  const int wr = wave >> 1;  // 0..3 -> 64-row strip (256 rows)
  const int wc = wave & 1;   // 0..1 -> 64-col strip (128 cols)
  const int brow = blockIdx.y;
  const int bcol = blockIdx.x;

  f32x4 acc[4][4];
#pragma unroll
  for (int m = 0; m < 4; ++m)
#pragma unroll
    for (int n = 0; n < 4; ++n) acc[m][n] = f32x4{0.f, 0.f, 0.f, 0.f};

  const unsigned char* srcA = A8 +
      (size_t)(2 * brow + (wave >> 2)) * PANEL_BYTES + (wave & 3) * 4096 +
      (lane << 4);
  const unsigned char* srcB =
      B8 + (size_t)bcol * PANEL_BYTES + wave * 2048 + (lane << 4);
  const int dA = (wave >> 2) * 16384 + (wave & 3) * 4096;
  const int dB = 32768 + wave * 2048;
  const unsigned char* ldsL = lds + (lane << 4);  // per-lane read base

  i32x8 fa0[4], fb0[4], fa1[4], fb1[4];

  // Prologue: stage tile0 -> buf0, tile1 -> buf1; wait tile0 (6 left in
  // flight); read tile0 fragments into set0.
  STAGE6(0, 0);
  STAGE6(BUFSZ, 1);
  asm volatile("s_waitcnt vmcnt(6)" ::: "memory");
  __builtin_amdgcn_s_barrier();
  __builtin_amdgcn_sched_barrier(0);
  READS(0, fa0, fb0);

  ITER(0, fa0, fb0, fa1, fb1)
  ITER(1, fa1, fb1, fa0, fb0)
  ITER(2, fa0, fb0, fa1, fb1)
  ITER(3, fa1, fb1, fa0, fb0)
  ITER(4, fa0, fb0, fa1, fb1)
  ITER(5, fa1, fb1, fa0, fb0)
  ITER(6, fa0, fb0, fa1, fb1)
  ITER(7, fa1, fb1, fa0, fb0)

  // Epilogue. C/D 16x16 map: col = lane&15, row = (lane>>4)*4 + r.
  const int rbase = brow * 256 + wr * 64 + (lane >> 4) * 4;
  const int cbase = bcol * 128 + wc * 64 + (lane & 15);
  float lsum;
  if ((bcol >> 1) == brow)  // 128-col strip overlaps the 256-row strip
    lsum = softplus_sum<true>(acc, rbase, cbase);
  else
    lsum = softplus_sum<false>(acc, rbase, cbase);

#pragma unroll
  for (int off = 32; off > 0; off >>= 1) lsum += __shfl_down(lsum, off);
  __syncthreads();
  if (lane == 0) wsum[wave] = lsum;
  __syncthreads();
  if (tid == 0) {
    float s = 0.f;
#pragma unroll
    for (int w = 0; w < 8; ++w) s += wsum[w];
    partials[blockIdx.y * gridDim.x + blockIdx.x] = s;
  }
}

__global__ void reduce_kernel(const float* __restrict__ partials, int n,
                              float* __restrict__ out) {
  __shared__ float s[256];
  float v = 0.f;
  for (int i = threadIdx.x; i < n; i += 256) v += partials[i];
  s[threadIdx.x] = v;
  __syncthreads();
  for (int off = 128; off > 0; off >>= 1) {
    if ((int)threadIdx.x < off) s[threadIdx.x] += s[threadIdx.x + off];
    __syncthreads();
  }
  if (threadIdx.x == 0) out[0] = s[0] / (float)B_DIM;
}

extern "C" void kernel_launch(void* const* d_in, const int* in_sizes, int n_in,
                              void* d_out, int out_size, void* d_ws, size_t ws_size,
                              hipStream_t stream) {
  const float* emb1 = (const float*)d_in[0];
  const float* emb2 = (const float*)d_in[1];

  unsigned char* A8 = (unsigned char*)d_ws;                // 8 MB (bricked)
  unsigned char* B8 = A8 + (size_t)B_DIM * K_DIM;          // 8 MB (bricked)
  float* partials = (float*)(B8 + (size_t)B_DIM * K_DIM);  // 8 KB

  const float INV_T = 1.0f / 0.07f;
  const int nbA = (B_DIM * K_DIM / 16) / 256;  // 2048 blocks per operand
  cvt_fused<<<2 * nbA, 256, 0, stream>>>(emb1, emb2, A8, B8, nbA, INV_T);

  dim3 grid(B_DIM / 128, B_DIM / 256);  // 64 x 32
  siglip_gemm<<<grid, 512, 0, stream>>>(A8, B8, partials);

  const int nparts = (B_DIM / 256) * (B_DIM / 128);
  reduce_kernel<<<1, 256, 0, stream>>>(partials, nparts, (float*)d_out);
}